// Round 13
// baseline (203.364 us; speedup 1.0000x reference)
//
#include <hip/hip_runtime.h>

// ---------------------------------------------------------------------------
// MultiHeadAttention graph-attention kernel for MI355X (gfx950).  Round 13.
// R12 + left-side message fusion:
//  - R_feat[N][1024] = nodeR @ [G; Wc]^T   (cols 0-511 KR2, 512-1023 VW_R)
//  - L_vw[N][512]    = nodeL @ Wc^T
//  - edge_left_fused: per left node, per edge gather ONE contiguous R_feat
//    row (score + message halves), compute w, accumulate left message, write
//    left output row directly; spill only right-side (w, src) pairs.
//  - node_msg_right: right nodes only, gathering the 20MB L_vw array.
// GEMM core: R6 2-buffer / counted vmcnt / zero-conflict swizzle 128^2 dual.
// ---------------------------------------------------------------------------

#define C_DIM 512
#define TEMP_INV (1.0f / 22.627416997969522f)   // 1/sqrt(512)

using bf16x8 = __attribute__((ext_vector_type(8))) __bf16;
using s16x8  = __attribute__((ext_vector_type(8))) short;
using s16x4  = __attribute__((ext_vector_type(4))) short;
using f32x4  = __attribute__((ext_vector_type(4))) float;

__device__ __forceinline__ float bf2f(short u) {
    union { unsigned u; float f; } t;
    t.u = ((unsigned)(unsigned short)u) << 16;
    return t.f;
}
__device__ __forceinline__ short f2bf(float f) {
    union { float f; unsigned u; } t;
    t.f = f;
    unsigned r = t.u + 0x7FFFu + ((t.u >> 16) & 1u);  // RNE
    return (short)(r >> 16);
}

// ------------- all fp32 -> bf16 converts in one dispatch --------------------
// blocks 0-2047: nodes (grid-stride); 2048-2111: Wv->WvT; 2112-2175: Wk->WkT;
// 2176-2239: Wo->WoB.
__global__ void cvt_all(const float* __restrict__ nodeL, const float* __restrict__ nodeR,
                        short* __restrict__ nodeLR,
                        const float* __restrict__ Wk, const float* __restrict__ Wv,
                        const float* __restrict__ Wo,
                        short* __restrict__ WkT, short* __restrict__ WvT,
                        short* __restrict__ WoB, long n4half) {
    int b = blockIdx.x;
    int tid = threadIdx.x;
    if (b < 2048) {
        long n4 = 2 * n4half;
        for (long i = (long)b * 256 + tid; i < n4; i += 2048L * 256) {
            const float4* src = (i < n4half)
                ? reinterpret_cast<const float4*>(nodeL) + i
                : reinterpret_cast<const float4*>(nodeR) + (i - n4half);
            float4 v = *src;
            s16x4 o;
            o[0] = f2bf(v.x); o[1] = f2bf(v.y); o[2] = f2bf(v.z); o[3] = f2bf(v.w);
            reinterpret_cast<s16x4*>(nodeLR)[i] = o;
        }
    } else if (b < 2176) {
        int bb = b - 2048;                    // 0-63 Wv, 64-127 Wk
        const float* src = (bb < 64) ? Wv : Wk;
        short* dst = (bb < 64) ? WvT : WkT;
        bb &= 63;
        __shared__ float t[64][65];
        int bx = bb & 7, by = bb >> 3;
#pragma unroll
        for (int i = 0; i < 4; ++i) {
            int idx = i * 256 + tid;
            int row = idx >> 4, c4 = idx & 15;
            float4 v = *(const float4*)&src[(size_t)(by * 64 + row) * 512 + bx * 64 + c4 * 4];
            t[row][c4 * 4 + 0] = v.x; t[row][c4 * 4 + 1] = v.y;
            t[row][c4 * 4 + 2] = v.z; t[row][c4 * 4 + 3] = v.w;
        }
        __syncthreads();
#pragma unroll
        for (int i = 0; i < 4; ++i) {
            int idx = i * 256 + tid;
            int row = idx >> 4, g = idx & 15;
            s16x4 o;
            o[0] = f2bf(t[g * 4 + 0][row]);
            o[1] = f2bf(t[g * 4 + 1][row]);
            o[2] = f2bf(t[g * 4 + 2][row]);
            o[3] = f2bf(t[g * 4 + 3][row]);
            *(s16x4*)&dst[(size_t)(bx * 64 + row) * 512 + by * 64 + g * 4] = o;
        }
    } else {
        long base = (long)(b - 2176) * 1024;   // float4 units
#pragma unroll
        for (int i = 0; i < 4; ++i) {
            long idx = base + i * 256 + tid;
            float4 v = reinterpret_cast<const float4*>(Wo)[idx];
            s16x4 o;
            o[0] = f2bf(v.x); o[1] = f2bf(v.y); o[2] = f2bf(v.z); o[3] = f2bf(v.w);
            reinterpret_cast<s16x4*>(WoB)[idx] = o;
        }
    }
}

// ---------------------------- dual bf16 GEMM --------------------------------
// Two GEMMs C = A @ B^T (K=512, per-sub col count NC) in one dispatch.
__global__ __launch_bounds__(256, 4)
void gemm_dual(const short* __restrict__ A0, const short* __restrict__ B0,
               short* __restrict__ C0, int M0, int NC0, int nn0, int t0,
               const short* __restrict__ A1, const short* __restrict__ B1,
               short* __restrict__ C1, int M1, int NC1, int nn1, int total) {
    __shared__ short As[2][128 * 32];
    __shared__ short Bs[2][128 * 32];

    // bijective XCD-chunked block swizzle (m204)
    const int bid = blockIdx.x;
    const int q = total >> 3, r = total & 7;
    const int xcd = bid & 7, idx = bid >> 3;
    const int swz = (xcd < r ? xcd * (q + 1) : r * (q + 1) + (xcd - r) * q) + idx;

    const short* A; const short* B; short* Cp; int M, NC, nn, tile;
    if (swz < t0) { A = A0; B = B0; Cp = C0; M = M0; NC = NC0; nn = nn0; tile = swz; }
    else          { A = A1; B = B1; Cp = C1; M = M1; NC = NC1; nn = nn1; tile = swz - t0; }
    const int bm = (tile / nn) * 128;
    const int bn = (tile % nn) * 128;
    const int K = C_DIM;

    const int tid  = threadIdx.x;
    const int lane = tid & 63;
    const int wid  = tid >> 6;
    const int wm   = (wid >> 1) * 64;
    const int wn   = (wid & 1) * 64;
    const int lrow  = lane & 15;
    const int khalf = lane >> 4;

    auto stage = [&](short* dA, short* dB, int k0) {
#pragma unroll
        for (int j = 0; j < 2; ++j) {
            int L    = j * 256 + tid;        // linear LDS granule 0..511
            int pr   = L >> 3;               // LDS row (128B)
            int slot = L & 7;
            int g    = slot ^ (pr & 7);      // logical granule
            int row  = pr * 2 + (g >> 2);    // tile row 0..127
            int kg   = g & 3;                // 16B col-granule
            int wb   = (j * 256 + (tid & ~63)) * 16;   // wave-uniform base
            {
                int grow = bm + row; if (grow >= M) grow = M - 1;
                const short* src = A + (size_t)grow * K + k0 + kg * 8;
                __builtin_amdgcn_global_load_lds(
                    (__attribute__((address_space(1))) void*)src,
                    (__attribute__((address_space(3))) void*)((char*)dA + wb),
                    16, 0, 0);
            }
            {
                int grow = bn + row;   // bn+row < NC always
                const short* src = B + (size_t)grow * K + k0 + kg * 8;
                __builtin_amdgcn_global_load_lds(
                    (__attribute__((address_space(1))) void*)src,
                    (__attribute__((address_space(3))) void*)((char*)dB + wb),
                    16, 0, 0);
            }
        }
    };

    auto frag = [&](const short* h, int row) -> bf16x8 {
        int pr   = row >> 1;
        int g    = ((row & 1) << 2) | khalf;
        int slot = g ^ (pr & 7);
        return *(const bf16x8*)&h[pr * 64 + slot * 8];
    };

    f32x4 acc[4][4] = {};
    const int nt = K >> 5;   // 16

    stage(As[0], Bs[0], 0);

    for (int t = 0; t < nt; ++t) {
        const int cur = t & 1;
        if (t + 1 < nt) {
            stage(As[cur ^ 1], Bs[cur ^ 1], (t + 1) << 5);
            asm volatile("s_waitcnt vmcnt(4)" ::: "memory");  // tile t landed
        } else {
            asm volatile("s_waitcnt vmcnt(0)" ::: "memory");
        }
        __builtin_amdgcn_s_barrier();                         // buf[cur] ready

        const short* as = As[cur];
        const short* bs = Bs[cur];
        bf16x8 af[4], bfr[4];
#pragma unroll
        for (int m = 0; m < 4; ++m) af[m] = frag(as, wm + m * 16 + lrow);
#pragma unroll
        for (int n = 0; n < 4; ++n) bfr[n] = frag(bs, wn + n * 16 + lrow);

        asm volatile("s_waitcnt lgkmcnt(0)" ::: "memory");
        __builtin_amdgcn_sched_barrier(0);
        __builtin_amdgcn_s_barrier();

        __builtin_amdgcn_s_setprio(1);
#pragma unroll
        for (int m = 0; m < 4; ++m)
#pragma unroll
            for (int n = 0; n < 4; ++n)
                acc[m][n] = __builtin_amdgcn_mfma_f32_16x16x32_bf16(
                    af[m], bfr[n], acc[m][n], 0, 0, 0);
        __builtin_amdgcn_s_setprio(0);
    }

    // epilogue: D mapping col=lane&15, row=(lane>>4)*4+r  [m89]
    const int crow0 = (lane >> 4) * 4;
    const int ccol  = lane & 15;
#pragma unroll
    for (int m = 0; m < 4; ++m) {
#pragma unroll
        for (int n = 0; n < 4; ++n) {
            int col = bn + wn + n * 16 + ccol;
#pragma unroll
            for (int r2 = 0; r2 < 4; ++r2) {
                int row = bm + wm + m * 16 + crow0 + r2;
                if (row < M) Cp[(size_t)row * NC + col] = f2bf(acc[m][n][r2]);
            }
        }
    }
}

// ----------------------- CSR degree count (seg only) ------------------------
__global__ void count_edges2(const int* __restrict__ segL, const int* __restrict__ segR,
                             int* __restrict__ cnt, int E, int N) {
    int i = blockIdx.x * blockDim.x + threadIdx.x;
    int st = gridDim.x * blockDim.x;
    for (; i < E; i += st) {
        atomicAdd(&cnt[segL[i]], 1);
        atomicAdd(&cnt[N + segR[i]], 1);
    }
}

// ------------------------------- CSR scan ----------------------------------
__global__ void scan_blocks(const int* __restrict__ cnt, int* __restrict__ off,
                            int* __restrict__ bsum, int n) {
    __shared__ int ws[4];
    int tid = threadIdx.x, lane = tid & 63, wid = tid >> 6;
    int i = blockIdx.x * 256 + tid;
    int x = (i < n) ? cnt[i] : 0;
    int v = x;
#pragma unroll
    for (int d = 1; d < 64; d <<= 1) {
        int t = __shfl_up(v, d, 64);
        if (lane >= d) v += t;
    }
    if (lane == 63) ws[wid] = v;
    __syncthreads();
    int woff = 0;
    for (int w = 0; w < wid; ++w) woff += ws[w];
    v += woff;
    if (i < n) off[i + 1] = v;
    if (tid == 255) bsum[blockIdx.x] = v;
}

__global__ void scan_tops(int* __restrict__ bsum, int nb) {
    __shared__ int ws[4];
    int tid = threadIdx.x, lane = tid & 63, wid = tid >> 6;
    int x = (tid < nb) ? bsum[tid] : 0;
    int v = x;
#pragma unroll
    for (int d = 1; d < 64; d <<= 1) {
        int t = __shfl_up(v, d, 64);
        if (lane >= d) v += t;
    }
    if (lane == 63) ws[wid] = v;
    __syncthreads();
    int woff = 0;
    for (int w = 0; w < wid; ++w) woff += ws[w];
    v += woff;
    if (tid < nb) bsum[tid] = v - x;
}

__global__ void scan_apply(int* __restrict__ off, const int* __restrict__ bsum,
                           int* __restrict__ cnt, int n) {
    int i = blockIdx.x * 256 + threadIdx.x;
    if (i < n) {
        off[i + 1] += bsum[blockIdx.x];
        cnt[i] = 0;                      // becomes the fill cursor
    }
    if (i == 0) off[0] = 0;
}

// -------- fill left edge lists: lstL[slot] = segR[e] ------------------------
__global__ void fill_lstL(const int* __restrict__ segL, const int* __restrict__ segR,
                          const int* __restrict__ off, int* __restrict__ curL,
                          int* __restrict__ lstL, int E) {
    int i = blockIdx.x * blockDim.x + threadIdx.x;
    int st = gridDim.x * blockDim.x;
    for (; i < E; i += st) {
        int sl = segL[i];
        int p = off[sl] + atomicAdd(&curL[sl], 1);
        lstL[p] = segR[i];
    }
}

// ---- per-LEFT-node: scores + left message + left output (fully fused) ------
// One wave per left node.  KL row register-resident.  Per edge: gather one
// contiguous R_feat row (KR2 half -> dot -> w; VW half -> accumulate).
// Writes left output row; spills (w, left-idx) to the right-side CSR slot.
__global__ void edge_left_fused(const short* __restrict__ nodeL,
                                const short* __restrict__ Rfeat,   // [N][1024]
                                const int* __restrict__ lstL,
                                const int* __restrict__ off, int* __restrict__ curR,
                                float2* __restrict__ pairs,
                                const float* __restrict__ bo,
                                float* __restrict__ out, int N) {
    int n = blockIdx.x * 4 + (threadIdx.x >> 6);
    if (n >= N) return;
    int lane = threadIdx.x & 63;
    int beg = off[n], end = off[n + 1];

    float acc[8] = {};
    float z = 0.f;
    if (beg < end) {
        s16x8 kl = *(const s16x8*)(nodeL + (size_t)n * 512 + lane * 8);
        float klf[8];
#pragma unroll
        for (int j = 0; j < 8; ++j) klf[j] = bf2f(kl[j]);

        for (int k0 = beg; k0 < end; k0 += 4) {
            int sr0, sr1, sr2, sr3;
            {
                int k = k0;                       sr0 = lstL[k];
                k = (k0 + 1 < end) ? k0 + 1 : k0; sr1 = lstL[k];
                k = (k0 + 2 < end) ? k0 + 2 : k0; sr2 = lstL[k];
                k = (k0 + 3 < end) ? k0 + 3 : k0; sr3 = lstL[k];
            }
            const short* r0 = Rfeat + (size_t)sr0 * 1024 + lane * 8;
            const short* r1 = Rfeat + (size_t)sr1 * 1024 + lane * 8;
            const short* r2 = Rfeat + (size_t)sr2 * 1024 + lane * 8;
            const short* r3 = Rfeat + (size_t)sr3 * 1024 + lane * 8;
            const s16x8 kr0 = *(const s16x8*)r0;
            const s16x8 kr1 = *(const s16x8*)r1;
            const s16x8 kr2 = *(const s16x8*)r2;
            const s16x8 kr3 = *(const s16x8*)r3;
            float sum[4] = {0.f, 0.f, 0.f, 0.f};
#pragma unroll
            for (int j = 0; j < 8; ++j) {
                sum[0] += klf[j] * bf2f(kr0[j]);
                sum[1] += klf[j] * bf2f(kr1[j]);
                sum[2] += klf[j] * bf2f(kr2[j]);
                sum[3] += klf[j] * bf2f(kr3[j]);
            }
#pragma unroll
            for (int o = 32; o > 0; o >>= 1)
#pragma unroll
                for (int t = 0; t < 4; ++t) sum[t] += __shfl_xor(sum[t], o, 64);
            // every lane now holds all 4 sums (butterfly allreduce)
            float w0 = __expf(sum[0] * TEMP_INV);
            float w1 = (k0 + 1 < end) ? __expf(sum[1] * TEMP_INV) : 0.f;
            float w2 = (k0 + 2 < end) ? __expf(sum[2] * TEMP_INV) : 0.f;
            float w3 = (k0 + 3 < end) ? __expf(sum[3] * TEMP_INV) : 0.f;
            z += (w0 + w1) + (w2 + w3);

            const s16x8 v0 = *(const s16x8*)(r0 + 512);
            const s16x8 v1 = *(const s16x8*)(r1 + 512);
            const s16x8 v2 = *(const s16x8*)(r2 + 512);
            const s16x8 v3 = *(const s16x8*)(r3 + 512);
#pragma unroll
            for (int j = 0; j < 8; ++j) {
                acc[j] += w0 * bf2f(v0[j]) + w1 * bf2f(v1[j]);
                acc[j] += w2 * bf2f(v2[j]) + w3 * bf2f(v3[j]);
            }

            if (lane < 4 && k0 + lane < end) {
                float w  = (lane == 0) ? w0 : (lane == 1) ? w1
                         : (lane == 2) ? w2 : w3;
                int  srx = (lane == 0) ? sr0 : (lane == 1) ? sr1
                         : (lane == 2) ? sr2 : sr3;
                int pr = off[N + srx] + atomicAdd(&curR[N + srx], 1);
                pairs[pr - 0] = make_float2(w, __int_as_float(n));
            }
        }
    }
    float inv = (z > 0.f) ? 1.f / z : 0.f;

    float4 bs0 = *(const float4*)&bo[lane * 8];
    float4 bs1 = *(const float4*)&bo[lane * 8 + 4];
    float bb[8] = {bs0.x, bs0.y, bs0.z, bs0.w, bs1.x, bs1.y, bs1.z, bs1.w};
    f32x4 h0, h1;
#pragma unroll
    for (int j = 0; j < 4; ++j) {
        float v = acc[j] * inv + bb[j];
        h0[j] = v >= 0.f ? v : 0.01f * v;   // LeakyReLU
    }
#pragma unroll
    for (int j = 0; j < 4; ++j) {
        float v = acc[4 + j] * inv + bb[4 + j];
        h1[j] = v >= 0.f ? v : 0.01f * v;
    }
    float* orow = out + (size_t)n * C_DIM + lane * 8;
    __builtin_nontemporal_store(h0, (f32x4*)&orow[0]);
    __builtin_nontemporal_store(h1, (f32x4*)&orow[4]);
}

// ------- per-RIGHT-node weighted L_vw sum + normalize + bias + LReLU --------
// pairs[off[N+n]..] hold (w, left_idx).  Gathers from L_vw [N][512].
__global__ void node_msg_right(const int* __restrict__ off,
                               const float2* __restrict__ pairs,
                               const short* __restrict__ Lvw,
                               const float* __restrict__ bo,
                               float* __restrict__ out, int N) {
    int n = blockIdx.x * 4 + (threadIdx.x >> 6);
    if (n >= N) return;
    int node = N + n;
    int lane = threadIdx.x & 63;
    int beg = off[node], end = off[node + 1];
    const short* VWp = Lvw + lane * 8;

    float acc[8] = {};
    float z = 0.f;
    int i = beg;
    for (; i + 3 < end; i += 4) {
        float2 p0 = pairs[i], p1 = pairs[i + 1];
        float2 p2 = pairs[i + 2], p3 = pairs[i + 3];
        const s16x8 v0 = *(const s16x8*)(VWp + (size_t)__float_as_int(p0.y) * 512);
        const s16x8 v1 = *(const s16x8*)(VWp + (size_t)__float_as_int(p1.y) * 512);
        const s16x8 v2 = *(const s16x8*)(VWp + (size_t)__float_as_int(p2.y) * 512);
        const s16x8 v3 = *(const s16x8*)(VWp + (size_t)__float_as_int(p3.y) * 512);
        z += (p0.x + p1.x) + (p2.x + p3.x);
#pragma unroll
        for (int j = 0; j < 8; ++j) {
            acc[j] += p0.x * bf2f(v0[j]) + p1.x * bf2f(v1[j]);
            acc[j] += p2.x * bf2f(v2[j]) + p3.x * bf2f(v3[j]);
        }
    }
    for (; i < end; ++i) {
        float2 p = pairs[i];
        const s16x8 v = *(const s16x8*)(VWp + (size_t)__float_as_int(p.y) * 512);
        z += p.x;
#pragma unroll
        for (int j = 0; j < 8; ++j) acc[j] += p.x * bf2f(v[j]);
    }
    float inv = (z > 0.f) ? 1.f / z : 0.f;

    float4 bs0 = *(const float4*)&bo[lane * 8];
    float4 bs1 = *(const float4*)&bo[lane * 8 + 4];
    float bb[8] = {bs0.x, bs0.y, bs0.z, bs0.w, bs1.x, bs1.y, bs1.z, bs1.w};
    f32x4 h0, h1;
#pragma unroll
    for (int j = 0; j < 4; ++j) {
        float v = acc[j] * inv + bb[j];
        h0[j] = v >= 0.f ? v : 0.01f * v;   // LeakyReLU
    }
#pragma unroll
    for (int j = 0; j < 4; ++j) {
        float v = acc[4 + j] * inv + bb[4 + j];
        h1[j] = v >= 0.f ? v : 0.01f * v;
    }
    float* orow = out + (size_t)node * C_DIM + lane * 8;
    __builtin_nontemporal_store(h0, (f32x4*)&orow[0]);
    __builtin_nontemporal_store(h1, (f32x4*)&orow[4]);
}

// ------------------------------- launcher ----------------------------------
extern "C" void kernel_launch(void* const* d_in, const int* in_sizes, int n_in,
                              void* d_out, int out_size, void* d_ws, size_t ws_size,
                              hipStream_t stream) {
    const float* node_left  = (const float*)d_in[0];
    const int*   segL       = (const int*)d_in[1];
    const float* node_right = (const float*)d_in[3];
    const int*   segR       = (const int*)d_in[4];
    const float* Wk         = (const float*)d_in[6];
    const float* Wv         = (const float*)d_in[7];
    const float* Wo         = (const float*)d_in[8];
    const float* bo         = (const float*)d_in[9];

    const int C = C_DIM;
    const int N = in_sizes[0] / C;   // 20000
    const int E = in_sizes[1];       // 160000
    const int NN2 = 2 * N;

    size_t offb = 0;
    auto alloc = [&](size_t bytes) -> void* {
        void* p = (char*)d_ws + offb;
        offb += (bytes + 255) & ~(size_t)255;
        return p;
    };
    short* nodeLR_b = (short*)alloc((size_t)NN2 * C * 2);   // [2N][512] bf16 nodes
    short* nodeL_b  = nodeLR_b;
    short* nodeR_b  = nodeLR_b + (size_t)N * C;
    short* WkT_b = (short*)alloc((size_t)C * C * 2);
    short* WvT_b = (short*)alloc((size_t)C * C * 2);
    short* Wo_b  = (short*)alloc((size_t)C * C * 2);
    short* WGc   = (short*)alloc((size_t)1024 * C * 2);     // [G; Wc] rows 0-1023
    short* Wc_b  = WGc + (size_t)C * C;                     // rows 512-1023 = Wc
    short* Rfeat = (short*)alloc((size_t)N * 1024 * 2);     // [KR2 | VW_R]
    short* Lvw   = (short*)alloc((size_t)N * C * 2);        // nodeL @ Wc^T
    float2* pairs = (float2*)alloc((size_t)2 * E * 8);      // only right slots used
    int* lstL = (int*)alloc((size_t)E * 4);
    int* cnt  = (int*)alloc((size_t)NN2 * 4);               // degree, then cursors
    int* off  = (int*)alloc((size_t)(NN2 + 1) * 4);
    int* bsum = (int*)alloc(256 * 4);

    const int nsb = (NN2 + 255) / 256;

    // 1. CSR degrees + scan (depends only on seg arrays), then left lists
    hipMemsetAsync(cnt, 0, (size_t)NN2 * 4, stream);
    count_edges2<<<512, 256, 0, stream>>>(segL, segR, cnt, E, N);
    scan_blocks<<<nsb, 256, 0, stream>>>(cnt, off, bsum, NN2);
    scan_tops<<<1, 256, 0, stream>>>(bsum, nsb);
    scan_apply<<<nsb, 256, 0, stream>>>(off, bsum, cnt, NN2);   // cnt -> cursors
    fill_lstL<<<512, 256, 0, stream>>>(segL, segR, off, cnt, lstL, E);

    // 2. all converts in one dispatch
    cvt_all<<<2240, 256, 0, stream>>>(node_left, node_right, nodeLR_b,
                                      Wk, Wv, Wo, WkT_b, WvT_b, Wo_b,
                                      (long)N * C / 4);

    // 3. small dual GEMM: G = Wk^T Wk -> WGc rows 0-511; Wc = Wo@Wv -> rows 512-1023
    gemm_dual<<<32, 256, 0, stream>>>(WkT_b, WkT_b, WGc, C, C, 4, 16,
                                      Wo_b, WvT_b, Wc_b, C, C, 4, 32);

    // 4. big dual GEMM: Rfeat = nodeR @ WGc^T (NC=1024), Lvw = nodeL @ Wc^T
    {
        int nmt = (N + 127) / 128;           // 157
        int t0 = nmt * 8;                    // Rfeat tiles
        int total = t0 + nmt * 4;            // + Lvw tiles
        gemm_dual<<<total, 256, 0, stream>>>(nodeR_b, WGc, Rfeat, N, 1024, 8, t0,
                                             nodeL_b, Wc_b, Lvw, N, 512, 4, total);
    }

    // 5. fused left pass: scores + left message + left output + right pairs
    edge_left_fused<<<(N + 3) / 4, 256, 0, stream>>>(nodeL_b, Rfeat, lstL, off,
                                                     cnt, pairs, bo,
                                                     (float*)d_out, N);

    // 6. right pass: weighted L_vw accumulate + bias + LeakyReLU
    node_msg_right<<<(N + 3) / 4, 256, 0, stream>>>(off, pairs, Lvw, bo,
                                                    (float*)d_out, N);
}

// Round 14
// 198.005 us; speedup vs baseline: 1.0271x; 1.0271x over previous
//
#include <hip/hip_runtime.h>

// ---------------------------------------------------------------------------
// MultiHeadAttention graph-attention kernel for MI355X (gfx950).  Round 14.
// = R12 (best: 201.3us) with launch consolidation: fill_lstL + all converts
//   in ONE dispatch (block-range split).  12 -> 10 dispatches.
// Pipeline:
//   1. memset cnt; count_edges2; 3-kernel hierarchical scan
//   2. fused {fill_lstL | node cvt | weight transposes/cvt}
//   3. dual GEMM small: Wc = Wo@Wv, G = Wk^T Wk
//   4. dual GEMM big:   VW = nodeLR @ Wc^T,  KR2 = nodeR @ G^T
//   5. edge_left: per-left-node scores (K-row register-resident) + pair fill
//   6. node_msg: per-node weighted VW sum + normalize + bias + LeakyReLU
// GEMM core: 128^2/BK=32, 2-buffer, counted vmcnt, zero-conflict LDS swizzle,
// bijective XCD block swizzle (structure ceiling ~626 TF for K=512).
// ---------------------------------------------------------------------------

#define C_DIM 512
#define TEMP_INV (1.0f / 22.627416997969522f)   // 1/sqrt(512)

using bf16x8 = __attribute__((ext_vector_type(8))) __bf16;
using s16x8  = __attribute__((ext_vector_type(8))) short;
using s16x4  = __attribute__((ext_vector_type(4))) short;
using f32x4  = __attribute__((ext_vector_type(4))) float;

__device__ __forceinline__ float bf2f(short u) {
    union { unsigned u; float f; } t;
    t.u = ((unsigned)(unsigned short)u) << 16;
    return t.f;
}
__device__ __forceinline__ short f2bf(float f) {
    union { float f; unsigned u; } t;
    t.f = f;
    unsigned r = t.u + 0x7FFFu + ((t.u >> 16) & 1u);  // RNE
    return (short)(r >> 16);
}

// ---- fused: fill_lstL (blocks 0-511) | node cvt (512-2559) |
//      Wv/Wk transpose-cvt (2560-2687) | Wo cvt (2688-2751) ----------------
__global__ void fill_and_cvt(const int* __restrict__ segL, const int* __restrict__ segR,
                             const int* __restrict__ off, int* __restrict__ curL,
                             int* __restrict__ lstL, int E,
                             const float* __restrict__ nodeL, const float* __restrict__ nodeR,
                             short* __restrict__ nodeLR,
                             const float* __restrict__ Wk, const float* __restrict__ Wv,
                             const float* __restrict__ Wo,
                             short* __restrict__ WkT, short* __restrict__ WvT,
                             short* __restrict__ WoB, long n4half) {
    int b = blockIdx.x;
    int tid = threadIdx.x;
    if (b < 512) {
        int st = 512 * 256;
        for (int i = b * 256 + tid; i < E; i += st) {
            int sl = segL[i];
            int p = off[sl] + atomicAdd(&curL[sl], 1);
            lstL[p] = segR[i];
        }
    } else if (b < 2560) {
        long n4 = 2 * n4half;
        for (long i = (long)(b - 512) * 256 + tid; i < n4; i += 2048L * 256) {
            const float4* src = (i < n4half)
                ? reinterpret_cast<const float4*>(nodeL) + i
                : reinterpret_cast<const float4*>(nodeR) + (i - n4half);
            float4 v = *src;
            s16x4 o;
            o[0] = f2bf(v.x); o[1] = f2bf(v.y); o[2] = f2bf(v.z); o[3] = f2bf(v.w);
            reinterpret_cast<s16x4*>(nodeLR)[i] = o;
        }
    } else if (b < 2688) {
        int bb = b - 2560;                    // 0-63 Wv, 64-127 Wk
        const float* src = (bb < 64) ? Wv : Wk;
        short* dst = (bb < 64) ? WvT : WkT;
        bb &= 63;
        __shared__ float t[64][65];
        int bx = bb & 7, by = bb >> 3;
#pragma unroll
        for (int i = 0; i < 4; ++i) {
            int idx = i * 256 + tid;
            int row = idx >> 4, c4 = idx & 15;
            float4 v = *(const float4*)&src[(size_t)(by * 64 + row) * 512 + bx * 64 + c4 * 4];
            t[row][c4 * 4 + 0] = v.x; t[row][c4 * 4 + 1] = v.y;
            t[row][c4 * 4 + 2] = v.z; t[row][c4 * 4 + 3] = v.w;
        }
        __syncthreads();
#pragma unroll
        for (int i = 0; i < 4; ++i) {
            int idx = i * 256 + tid;
            int row = idx >> 4, g = idx & 15;
            s16x4 o;
            o[0] = f2bf(t[g * 4 + 0][row]);
            o[1] = f2bf(t[g * 4 + 1][row]);
            o[2] = f2bf(t[g * 4 + 2][row]);
            o[3] = f2bf(t[g * 4 + 3][row]);
            *(s16x4*)&dst[(size_t)(bx * 64 + row) * 512 + by * 64 + g * 4] = o;
        }
    } else {
        long base = (long)(b - 2688) * 1024;   // float4 units
#pragma unroll
        for (int i = 0; i < 4; ++i) {
            long idx = base + i * 256 + tid;
            float4 v = reinterpret_cast<const float4*>(Wo)[idx];
            s16x4 o;
            o[0] = f2bf(v.x); o[1] = f2bf(v.y); o[2] = f2bf(v.z); o[3] = f2bf(v.w);
            reinterpret_cast<s16x4*>(WoB)[idx] = o;
        }
    }
}

// ---------------------------- dual bf16 GEMM --------------------------------
// Two GEMMs C = A @ B^T (N=K=512) in one dispatch; block < t0 -> GEMM0.
__global__ __launch_bounds__(256, 4)
void gemm_dual(const short* __restrict__ A0, const short* __restrict__ B0,
               short* __restrict__ C0, int M0, int t0,
               const short* __restrict__ A1, const short* __restrict__ B1,
               short* __restrict__ C1, int M1, int total) {
    __shared__ short As[2][128 * 32];
    __shared__ short Bs[2][128 * 32];

    // bijective XCD-chunked block swizzle (m204)
    const int bid = blockIdx.x;
    const int q = total >> 3, r = total & 7;
    const int xcd = bid & 7, idx = bid >> 3;
    const int swz = (xcd < r ? xcd * (q + 1) : r * (q + 1) + (xcd - r) * q) + idx;

    const short* A; const short* B; short* Cp; int M; int tile;
    if (swz < t0) { A = A0; B = B0; Cp = C0; M = M0; tile = swz; }
    else          { A = A1; B = B1; Cp = C1; M = M1; tile = swz - t0; }
    const int bm = (tile >> 2) * 128;      // nn = 512/128 = 4
    const int bn = (tile & 3) * 128;
    const int K = C_DIM;

    const int tid  = threadIdx.x;
    const int lane = tid & 63;
    const int wid  = tid >> 6;
    const int wm   = (wid >> 1) * 64;
    const int wn   = (wid & 1) * 64;
    const int lrow  = lane & 15;
    const int khalf = lane >> 4;

    auto stage = [&](short* dA, short* dB, int k0) {
#pragma unroll
        for (int j = 0; j < 2; ++j) {
            int L    = j * 256 + tid;        // linear LDS granule 0..511
            int pr   = L >> 3;               // LDS row (128B)
            int slot = L & 7;
            int g    = slot ^ (pr & 7);      // logical granule
            int row  = pr * 2 + (g >> 2);    // tile row 0..127
            int kg   = g & 3;                // 16B col-granule
            int wb   = (j * 256 + (tid & ~63)) * 16;   // wave-uniform base
            {
                int grow = bm + row; if (grow >= M) grow = M - 1;
                const short* src = A + (size_t)grow * K + k0 + kg * 8;
                __builtin_amdgcn_global_load_lds(
                    (__attribute__((address_space(1))) void*)src,
                    (__attribute__((address_space(3))) void*)((char*)dA + wb),
                    16, 0, 0);
            }
            {
                int grow = bn + row;   // N = 512, always in range
                const short* src = B + (size_t)grow * K + k0 + kg * 8;
                __builtin_amdgcn_global_load_lds(
                    (__attribute__((address_space(1))) void*)src,
                    (__attribute__((address_space(3))) void*)((char*)dB + wb),
                    16, 0, 0);
            }
        }
    };

    auto frag = [&](const short* h, int row) -> bf16x8 {
        int pr   = row >> 1;
        int g    = ((row & 1) << 2) | khalf;
        int slot = g ^ (pr & 7);
        return *(const bf16x8*)&h[pr * 64 + slot * 8];
    };

    f32x4 acc[4][4] = {};
    const int nt = K >> 5;   // 16

    stage(As[0], Bs[0], 0);

    for (int t = 0; t < nt; ++t) {
        const int cur = t & 1;
        if (t + 1 < nt) {
            stage(As[cur ^ 1], Bs[cur ^ 1], (t + 1) << 5);
            asm volatile("s_waitcnt vmcnt(4)" ::: "memory");  // tile t landed
        } else {
            asm volatile("s_waitcnt vmcnt(0)" ::: "memory");
        }
        __builtin_amdgcn_s_barrier();                         // buf[cur] ready

        const short* as = As[cur];
        const short* bs = Bs[cur];
        bf16x8 af[4], bfr[4];
#pragma unroll
        for (int m = 0; m < 4; ++m) af[m] = frag(as, wm + m * 16 + lrow);
#pragma unroll
        for (int n = 0; n < 4; ++n) bfr[n] = frag(bs, wn + n * 16 + lrow);

        asm volatile("s_waitcnt lgkmcnt(0)" ::: "memory");
        __builtin_amdgcn_sched_barrier(0);
        __builtin_amdgcn_s_barrier();

        __builtin_amdgcn_s_setprio(1);
#pragma unroll
        for (int m = 0; m < 4; ++m)
#pragma unroll
            for (int n = 0; n < 4; ++n)
                acc[m][n] = __builtin_amdgcn_mfma_f32_16x16x32_bf16(
                    af[m], bfr[n], acc[m][n], 0, 0, 0);
        __builtin_amdgcn_s_setprio(0);
    }

    // epilogue: D mapping col=lane&15, row=(lane>>4)*4+r  [m89]
    const int crow0 = (lane >> 4) * 4;
    const int ccol  = lane & 15;
#pragma unroll
    for (int m = 0; m < 4; ++m) {
#pragma unroll
        for (int n = 0; n < 4; ++n) {
            int col = bn + wn + n * 16 + ccol;
#pragma unroll
            for (int r2 = 0; r2 < 4; ++r2) {
                int row = bm + wm + m * 16 + crow0 + r2;
                if (row < M) Cp[(size_t)row * C_DIM + col] = f2bf(acc[m][n][r2]);
            }
        }
    }
}

// ----------------------- CSR degree count (seg only) ------------------------
__global__ void count_edges2(const int* __restrict__ segL, const int* __restrict__ segR,
                             int* __restrict__ cnt, int E, int N) {
    int i = blockIdx.x * blockDim.x + threadIdx.x;
    int st = gridDim.x * blockDim.x;
    for (; i < E; i += st) {
        atomicAdd(&cnt[segL[i]], 1);
        atomicAdd(&cnt[N + segR[i]], 1);
    }
}

// ------------------------------- CSR scan ----------------------------------
__global__ void scan_blocks(const int* __restrict__ cnt, int* __restrict__ off,
                            int* __restrict__ bsum, int n) {
    __shared__ int ws[4];
    int tid = threadIdx.x, lane = tid & 63, wid = tid >> 6;
    int i = blockIdx.x * 256 + tid;
    int x = (i < n) ? cnt[i] : 0;
    int v = x;
#pragma unroll
    for (int d = 1; d < 64; d <<= 1) {
        int t = __shfl_up(v, d, 64);
        if (lane >= d) v += t;
    }
    if (lane == 63) ws[wid] = v;
    __syncthreads();
    int woff = 0;
    for (int w = 0; w < wid; ++w) woff += ws[w];
    v += woff;
    if (i < n) off[i + 1] = v;
    if (tid == 255) bsum[blockIdx.x] = v;
}

__global__ void scan_tops(int* __restrict__ bsum, int nb) {
    __shared__ int ws[4];
    int tid = threadIdx.x, lane = tid & 63, wid = tid >> 6;
    int x = (tid < nb) ? bsum[tid] : 0;
    int v = x;
#pragma unroll
    for (int d = 1; d < 64; d <<= 1) {
        int t = __shfl_up(v, d, 64);
        if (lane >= d) v += t;
    }
    if (lane == 63) ws[wid] = v;
    __syncthreads();
    int woff = 0;
    for (int w = 0; w < wid; ++w) woff += ws[w];
    v += woff;
    if (tid < nb) bsum[tid] = v - x;
}

__global__ void scan_apply(int* __restrict__ off, const int* __restrict__ bsum,
                           int* __restrict__ cnt, int n) {
    int i = blockIdx.x * 256 + threadIdx.x;
    if (i < n) {
        off[i + 1] += bsum[blockIdx.x];
        cnt[i] = 0;                      // becomes the fill cursor
    }
    if (i == 0) off[0] = 0;
}

// ------ per-LEFT-node edge scores + pair fill (K-row register-resident) -----
__global__ void edge_left(const short* __restrict__ nodeL,
                          const short* __restrict__ KR2,
                          const int* __restrict__ lstL,
                          const int* __restrict__ off, int* __restrict__ curR,
                          float2* __restrict__ pairs, int N) {
    int n = blockIdx.x * 4 + (threadIdx.x >> 6);
    if (n >= N) return;
    int lane = threadIdx.x & 63;
    int beg = off[n], end = off[n + 1];
    if (beg == end) return;

    s16x8 kl = *(const s16x8*)(nodeL + (size_t)n * 512 + lane * 8);
    float klf[8];
#pragma unroll
    for (int j = 0; j < 8; ++j) klf[j] = bf2f(kl[j]);

    for (int k0 = beg; k0 < end; k0 += 4) {
        int sr0, sr1, sr2, sr3;
        float sum[4];
        {
            int k = k0;                       sr0 = lstL[k];
            k = (k0 + 1 < end) ? k0 + 1 : k0; sr1 = lstL[k];
            k = (k0 + 2 < end) ? k0 + 2 : k0; sr2 = lstL[k];
            k = (k0 + 3 < end) ? k0 + 3 : k0; sr3 = lstL[k];
        }
        const s16x8 kr0 = *(const s16x8*)(KR2 + (size_t)sr0 * 512 + lane * 8);
        const s16x8 kr1 = *(const s16x8*)(KR2 + (size_t)sr1 * 512 + lane * 8);
        const s16x8 kr2 = *(const s16x8*)(KR2 + (size_t)sr2 * 512 + lane * 8);
        const s16x8 kr3 = *(const s16x8*)(KR2 + (size_t)sr3 * 512 + lane * 8);
        float s0 = 0.f, s1 = 0.f, s2 = 0.f, s3 = 0.f;
#pragma unroll
        for (int j = 0; j < 8; ++j) {
            s0 += klf[j] * bf2f(kr0[j]);
            s1 += klf[j] * bf2f(kr1[j]);
            s2 += klf[j] * bf2f(kr2[j]);
            s3 += klf[j] * bf2f(kr3[j]);
        }
        sum[0] = s0; sum[1] = s1; sum[2] = s2; sum[3] = s3;
#pragma unroll
        for (int o = 32; o > 0; o >>= 1)
#pragma unroll
            for (int t = 0; t < 4; ++t) sum[t] += __shfl_xor(sum[t], o, 64);

        if (lane < 4 && k0 + lane < end) {
            float s  = (lane == 0) ? sum[0] : (lane == 1) ? sum[1]
                     : (lane == 2) ? sum[2] : sum[3];
            int  srx = (lane == 0) ? sr0 : (lane == 1) ? sr1
                     : (lane == 2) ? sr2 : sr3;
            float w = __expf(s * TEMP_INV);
            pairs[k0 + lane] = make_float2(w, __int_as_float(N + srx));  // L slot
            int pr = off[N + srx] + atomicAdd(&curR[N + srx], 1);
            pairs[pr] = make_float2(w, __int_as_float(n));               // R slot
        }
    }
}

// --------- per-node weighted VW sum + normalize + bias + LeakyReLU ----------
__global__ void node_msg(const int* __restrict__ off,
                         const float2* __restrict__ pairs,
                         const short* __restrict__ VW,
                         const float* __restrict__ bo,
                         float* __restrict__ out, int NN2) {
    int n = blockIdx.x * 4 + (threadIdx.x >> 6);
    if (n >= NN2) return;
    int lane = threadIdx.x & 63;
    int beg = off[n], end = off[n + 1];
    const short* VWp = VW + lane * 8;

    float acc[8] = {};
    float z = 0.f;
    int i = beg;
    for (; i + 3 < end; i += 4) {
        float2 p0 = pairs[i], p1 = pairs[i + 1];
        float2 p2 = pairs[i + 2], p3 = pairs[i + 3];
        const s16x8 v0 = *(const s16x8*)(VWp + (size_t)__float_as_int(p0.y) * 512);
        const s16x8 v1 = *(const s16x8*)(VWp + (size_t)__float_as_int(p1.y) * 512);
        const s16x8 v2 = *(const s16x8*)(VWp + (size_t)__float_as_int(p2.y) * 512);
        const s16x8 v3 = *(const s16x8*)(VWp + (size_t)__float_as_int(p3.y) * 512);
        z += (p0.x + p1.x) + (p2.x + p3.x);
#pragma unroll
        for (int j = 0; j < 8; ++j) {
            acc[j] += p0.x * bf2f(v0[j]) + p1.x * bf2f(v1[j]);
            acc[j] += p2.x * bf2f(v2[j]) + p3.x * bf2f(v3[j]);
        }
    }
    for (; i < end; ++i) {
        float2 p = pairs[i];
        const s16x8 v = *(const s16x8*)(VWp + (size_t)__float_as_int(p.y) * 512);
        z += p.x;
#pragma unroll
        for (int j = 0; j < 8; ++j) acc[j] += p.x * bf2f(v[j]);
    }
    float inv = (z > 0.f) ? 1.f / z : 0.f;

    float4 bs0 = *(const float4*)&bo[lane * 8];
    float4 bs1 = *(const float4*)&bo[lane * 8 + 4];
    float bb[8] = {bs0.x, bs0.y, bs0.z, bs0.w, bs1.x, bs1.y, bs1.z, bs1.w};
    f32x4 h0, h1;
#pragma unroll
    for (int j = 0; j < 4; ++j) {
        float v = acc[j] * inv + bb[j];
        h0[j] = v >= 0.f ? v : 0.01f * v;   // LeakyReLU
    }
#pragma unroll
    for (int j = 0; j < 4; ++j) {
        float v = acc[4 + j] * inv + bb[4 + j];
        h1[j] = v >= 0.f ? v : 0.01f * v;
    }
    float* orow = out + (size_t)n * C_DIM + lane * 8;
    __builtin_nontemporal_store(h0, (f32x4*)&orow[0]);
    __builtin_nontemporal_store(h1, (f32x4*)&orow[4]);
}

// ------------------------------- launcher ----------------------------------
extern "C" void kernel_launch(void* const* d_in, const int* in_sizes, int n_in,
                              void* d_out, int out_size, void* d_ws, size_t ws_size,
                              hipStream_t stream) {
    const float* node_left  = (const float*)d_in[0];
    const int*   segL       = (const int*)d_in[1];
    const float* node_right = (const float*)d_in[3];
    const int*   segR       = (const int*)d_in[4];
    const float* Wk         = (const float*)d_in[6];
    const float* Wv         = (const float*)d_in[7];
    const float* Wo         = (const float*)d_in[8];
    const float* bo         = (const float*)d_in[9];

    const int C = C_DIM;
    const int N = in_sizes[0] / C;   // 20000
    const int E = in_sizes[1];       // 160000
    const int NN2 = 2 * N;

    size_t offb = 0;
    auto alloc = [&](size_t bytes) -> void* {
        void* p = (char*)d_ws + offb;
        offb += (bytes + 255) & ~(size_t)255;
        return p;
    };
    short* nodeLR_b = (short*)alloc((size_t)NN2 * C * 2);   // [2N][512] bf16 nodes
    short* nodeL_b  = nodeLR_b;
    short* nodeR_b  = nodeLR_b + (size_t)N * C;
    short* WkT_b = (short*)alloc((size_t)C * C * 2);
    short* WvT_b = (short*)alloc((size_t)C * C * 2);
    short* Wo_b  = (short*)alloc((size_t)C * C * 2);
    short* Wc_b  = (short*)alloc((size_t)C * C * 2);        // Wo @ Wv
    short* G_b   = (short*)alloc((size_t)C * C * 2);        // Wk^T Wk
    short* VW    = (short*)alloc((size_t)NN2 * C * 2);      // nodeLR @ Wc^T, bf16
    short* KR2   = (short*)alloc((size_t)N * C * 2);        // nodeR @ G, bf16
    float2* pairs = (float2*)alloc((size_t)2 * E * 8);
    int* lstL = (int*)alloc((size_t)E * 4);
    int* cnt  = (int*)alloc((size_t)NN2 * 4);               // degree, then cursors
    int* off  = (int*)alloc((size_t)(NN2 + 1) * 4);
    int* bsum = (int*)alloc(256 * 4);

    const int nsb = (NN2 + 255) / 256;

    // 1. CSR degrees + scan (depends only on seg arrays)
    hipMemsetAsync(cnt, 0, (size_t)NN2 * 4, stream);
    count_edges2<<<512, 256, 0, stream>>>(segL, segR, cnt, E, N);
    scan_blocks<<<nsb, 256, 0, stream>>>(cnt, off, bsum, NN2);
    scan_tops<<<1, 256, 0, stream>>>(bsum, nsb);
    scan_apply<<<nsb, 256, 0, stream>>>(off, bsum, cnt, NN2);   // cnt -> cursors

    // 2. fused: fill left lists + all fp32->bf16 converts
    fill_and_cvt<<<2752, 256, 0, stream>>>(segL, segR, off, cnt, lstL, E,
                                           node_left, node_right, nodeLR_b,
                                           Wk, Wv, Wo, WkT_b, WvT_b, Wo_b,
                                           (long)N * C / 4);

    // 3. small dual GEMM: Wc = Wo @ Wv,  G = Wk^T Wk
    gemm_dual<<<32, 256, 0, stream>>>(Wo_b, WvT_b, Wc_b, C, 16,
                                      WkT_b, WkT_b, G_b, C, 32);

    // 4. big dual GEMM: VW = nodeLR @ Wc^T (M=2N),  KR2 = nodeR @ G^T (M=N)
    {
        int t0 = ((NN2 + 127) / 128) * 4;
        int total = t0 + ((N + 127) / 128) * 4;
        gemm_dual<<<total, 256, 0, stream>>>(nodeLR_b, Wc_b, VW, NN2, t0,
                                             nodeR_b, G_b, KR2, N, total);
    }

    // 5. per-left-node edge scores + pair fill
    edge_left<<<(N + 3) / 4, 256, 0, stream>>>(nodeL_b, KR2, lstL, off, cnt,
                                               pairs, N);

    // 6. per-node weighted VW accumulate + bias + LeakyReLU -> d_out
    node_msg<<<(NN2 + 3) / 4, 256, 0, stream>>>(off, pairs, VW, bo,
                                                (float*)d_out, NN2);
}